// Round 15
// baseline (166.333 us; speedup 1.0000x reference)
//
#include <hip/hip_runtime.h>
#include <math.h>

#define KW 65
#define L_LEN 65536
#define B_N 32
#define OC_N 64
#define KPAD 160      // two 80-wide channel sections
#define SEC 80
#define LT 128        // l per tile
#define NT 8          // tiles per block
#define LGRP (LT*NT)  // 1024 l per block
#define XW 216        // staged shorts per (phase, ch)

typedef __attribute__((ext_vector_type(8))) short short8;
typedef __attribute__((ext_vector_type(4))) short short4v;
typedef __attribute__((ext_vector_type(4))) float f32x4;

__device__ __forceinline__ unsigned short f2bf(float f) {
    unsigned u = __builtin_bit_cast(unsigned, f);
    unsigned r = u + 0x7FFFu + ((u >> 16) & 1u);
    return (unsigned short)(r >> 16);
}

__device__ __forceinline__ unsigned pk2(float a, float b) {
    return (unsigned)f2bf(a) | ((unsigned)f2bf(b) << 16);
}

__device__ __forceinline__ float nan0(float v) {
    if (isnan(v)) return 0.0f;
    if (isinf(v)) return v > 0.0f ? 3.4028234663852886e38f : -3.4028234663852886e38f;
    return v;
}

// ---------------- Kernel A: steered weights, packed bf16 [B][OC][160] -------
// grid (8, B): block handles batch b x 8 ocs -> short latency chains.
__global__ __launch_bounds__(256) void steer_weights(
        const int* __restrict__ z, const float* __restrict__ s,
        const float* __restrict__ bw, unsigned short* __restrict__ wpk) {
    const float PI = 3.14159265358979323846f;
    const float FS = 50000000.0f;
    int ocg = blockIdx.x;
    int b   = blockIdx.y;
    int t   = threadIdx.x;

    const int*   zb = z + b * 5;
    const float* sb = s + b * 5;
    float f0    = (zb[0] > 0) ? nan0(sb[0]) : 0.0f;
    float alpha = (zb[1] > 0) ? nan0(sb[1]) : 1.0f;
    float gain  = (zb[2] > 0) ? nan0(sb[2]) : 1.0f;
    float shf   = (zb[3] > 0) ? nan0(sb[3]) : 0.0f;
    float chirp = (zb[4] > 0) ? nan0(sb[4]) : 0.0f;

    float a = fmaxf(alpha, 0.001f);
    float Nf_raw = rintf(65.0f / a);          // jnp.round = half-to-even
    int   N  = (int)fminf(fmaxf(Nf_raw, 1.0f), 130.0f);
    float Nf = (float)N;
    int   sh = (int)rintf(shf);

    __shared__ float rw[8][2][KW];
    __shared__ float cph[KW], sph[KW];
    __shared__ int   j0t[KW], j1t[KW];
    __shared__ float w2t[KW];
    __shared__ int   i0t[130], i1t[130];
    __shared__ float w1t[130];

    if (t < KW) {
        float n  = (float)t;
        float tt = n / FS;
        float phi = 2.0f * PI * f0 * n / FS + PI * chirp * tt * tt;
        cph[t] = cosf(phi);
        sph[t] = sinf(phi);
        float c2  = fmaxf(((float)t + 0.5f) * (Nf / 65.0f) - 0.5f, 0.0f);
        float j0f = floorf(c2);
        j0t[t] = (int)j0f;
        j1t[t] = min((int)j0f + 1, N - 1);
        w2t[t] = c2 - j0f;
    } else if (t < KW + 130) {
        int j = t - KW;
        float c   = fmaxf(((float)j + 0.5f) * (65.0f / Nf) - 0.5f, 0.0f);
        float i0f = floorf(c);
        int   i0  = min((int)i0f, KW - 1);
        i0t[j] = i0;
        i1t[j] = min(i0 + 1, KW - 1);
        w1t[j] = c - i0f;
    }
    __syncthreads();

    // resample: 16 rows x 65 taps via table lerps
    for (int item = t; item < 16 * KW; item += 256) {
        int row = item / KW, i = item % KW;     // row = ocl*2 + ch
        const float* w = bw + (((ocg * 8 + (row >> 1)) * 2) + (row & 1)) * KW;
        int j0 = j0t[i], j1 = j1t[i];
        float v0 = (1.0f - w1t[j0]) * w[i0t[j0]] + w1t[j0] * w[i1t[j0]];
        float v1 = (1.0f - w1t[j1]) * w[i0t[j1]] + w1t[j1] * w[i1t[j1]];
        rw[row >> 1][row & 1][i] = (1.0f - w2t[i]) * v0 + w2t[i] * v1;
    }
    __syncthreads();

    int sh0 = ((sh % KW) + KW) % KW;
    // mix + gain + shift + pack
    for (int item = t; item < 8 * KW; item += 256) {
        int ocl = item / KW, k = item % KW;
        unsigned short* ob = wpk + ((size_t)b * OC_N + ocg * 8 + ocl) * KPAD;
        float I = rw[ocl][0][k], Q = rw[ocl][1][k];
        float cp = cph[k], sp = sph[k];
        float Ip = (I * cp - Q * sp) * gain;
        float Qp = (I * sp + Q * cp) * gain;
        int kk = k + sh0; if (kk >= KW) kk -= KW;
        ob[kk]       = f2bf(Ip);
        ob[SEC + kk] = f2bf(Qp);
    }
    // zero padding taps 65..79 of both sections
    for (int item = t; item < 8 * 30; item += 256) {
        int ocl = item / 30, rem = item % 30;
        int sec = rem / 15, kk = KW + rem % 15;
        unsigned short* ob = wpk + ((size_t)b * OC_N + ocg * 8 + ocl) * KPAD;
        ob[sec * SEC + kk] = 0;
    }
}

// ---------------- Kernel B: implicit-GEMM conv via bf16 MFMA -----------------
// R12 math verbatim in 128-THREAD blocks: 64 oc x 1024 l per block (8 tiles
// of 128), 2 waves = oc halves, 4-phase funnel LDS (6.9 KB), l = 64q+4c+p,
// contiguous f32x4 stores, 2 __syncthreads/tile. 6 independent 2-wave
// barrier domains per CU (vs 3 four-wave) desynchronize store bursts.
__global__ __launch_bounds__(128, 3) void steer_conv_mfma(
        const float* __restrict__ x, const unsigned short* __restrict__ wpk,
        float* __restrict__ y) {
    int b   = blockIdx.y;
    int L0  = blockIdx.x * LGRP;
    int tid = threadIdx.x;
    int wv = tid >> 6, lane = tid & 63;
    int c = lane & 15, g = lane >> 4;
    int a = wv;                     // oc half

    __shared__ __align__(16) unsigned short xt[2][4][2][XW];  // 6.9 KB

    // A fragments (weights) loaded once per block
    short8 afr[2][5];
    #pragma unroll
    for (int ot = 0; ot < 2; ++ot) {
        const unsigned short* wb = wpk + ((size_t)b * OC_N + 32 * a + 16 * ot + c) * KPAD;
        #pragma unroll
        for (int s = 0; s < 5; ++s)
            afr[ot][s] = *(const short8*)(wb + 32 * s + 8 * g);
    }

    const float* xb = x + (size_t)b * 2 * L_LEN;

    // loaders: 54 threads (tid 52..105), each owns 8 floats of one channel
    bool isLdr = (tid >= 52 && tid < 106);
    int lch = (tid - 52) / 27, li8 = (tid - 52) % 27;

    // per-lane B-fragment base (shorts) within a phase copy;
    // actual read at boff[s] + 64*q + 4*c (8B aligned)
    int boff[5];
    #pragma unroll
    for (int s = 0; s < 5; ++s) {
        int k0 = 32 * s + 8 * g;
        int ch = (k0 >= SEC) ? 1 : 0;
        int t0 = k0 - SEC * ch;
        boff[s] = ch * XW + t0;
    }

    auto ldf4 = [&](int gi) -> float4 {
        if (gi >= 0 && gi + 3 < L_LEN)
            return *(const float4*)(xb + (size_t)lch * L_LEN + gi);
        float tmp[4];
        #pragma unroll
        for (int u = 0; u < 4; ++u) {
            int q = gi + u;
            tmp[u] = (q >= 0 && q < L_LEN) ? xb[(size_t)lch * L_LEN + q] : 0.0f;
        }
        return make_float4(tmp[0], tmp[1], tmp[2], tmp[3]);
    };

    float4 va = make_float4(0.f, 0.f, 0.f, 0.f), vb = va;
    if (isLdr) {
        int gi0 = L0 - 32 + 8 * li8;
        va = ldf4(gi0);
        vb = ldf4(gi0 + 4);
    }

    int cur = 0;
    for (int t = 0; t < NT; ++t) {
        int l0 = L0 + t * LT;
        // stage bf16 base copy (phase 0): one uint4 per loader thread
        if (isLdr) {
            uint4 o = make_uint4(pk2(va.x, va.y), pk2(va.z, va.w),
                                 pk2(vb.x, vb.y), pk2(vb.z, vb.w));
            *(uint4*)&xt[cur][0][lch][8 * li8] = o;
        }
        __syncthreads();
        if (tid < 52) {
            // build phases 1..3 by 16-bit funnel shifts of the base copy
            int ch = tid / 26, j = tid % 26;
            const unsigned* src = (const unsigned*)&xt[cur][0][ch][8 * j];
            unsigned d[8];
            #pragma unroll
            for (int i = 0; i < 8; ++i) d[i] = src[i];
            #pragma unroll
            for (int p = 1; p < 4; ++p) {
                int q = p >> 1;
                unsigned o[4];
                #pragma unroll
                for (int i = 0; i < 4; ++i)
                    o[i] = (p & 1) ? ((d[i + q] >> 16) | (d[i + q + 1] << 16)) : d[i + q];
                *(uint4*)&xt[cur][p][ch][8 * j] = make_uint4(o[0], o[1], o[2], o[3]);
            }
        } else if (isLdr && t + 1 < NT) {
            // prefetch next tile's window into registers
            int gi0 = l0 + LT - 32 + 8 * li8;
            va = ldf4(gi0);
            vb = ldf4(gi0 + 4);
        }
        __syncthreads();

        f32x4 acc[2][2][4];   // [ot][q][p]
        #pragma unroll
        for (int ot = 0; ot < 2; ++ot)
            #pragma unroll
            for (int q = 0; q < 2; ++q)
                #pragma unroll
                for (int p = 0; p < 4; ++p) acc[ot][q][p] = (f32x4){0.f, 0.f, 0.f, 0.f};

        #pragma unroll
        for (int q = 0; q < 2; ++q) {
            #pragma unroll
            for (int p = 0; p < 4; ++p) {
                const unsigned short* xp = &xt[cur][p][0][0] + 64 * q + 4 * c;
                #pragma unroll
                for (int s = 0; s < 5; ++s) {
                    union { short4v h[2]; short8 v8; } u;
                    u.h[0] = *(const short4v*)(xp + boff[s]);
                    u.h[1] = *(const short4v*)(xp + boff[s] + 4);
                    short8 bfr = u.v8;
                    acc[0][q][p] = __builtin_amdgcn_mfma_f32_16x16x32_bf16(afr[0][s], bfr, acc[0][q][p], 0, 0, 0);
                    acc[1][q][p] = __builtin_amdgcn_mfma_f32_16x16x32_bf16(afr[1][s], bfr, acc[1][q][p], 0, 0, 0);
                }
            }
        }

        // store: per (ot,q,r) one contiguous f32x4 at l = l0 + 64q + 4c
        #pragma unroll
        for (int ot = 0; ot < 2; ++ot) {
            #pragma unroll
            for (int q = 0; q < 2; ++q) {
                #pragma unroll
                for (int r = 0; r < 4; ++r) {
                    int oc = 32 * a + 16 * ot + 4 * g + r;
                    float* yr = y + ((size_t)b * OC_N + oc) * L_LEN + l0 + 64 * q + 4 * c;
                    *(f32x4*)yr = (f32x4){ acc[ot][q][0][r], acc[ot][q][1][r],
                                           acc[ot][q][2][r], acc[ot][q][3][r] };
                }
            }
        }
        cur ^= 1;
    }
}

extern "C" void kernel_launch(void* const* d_in, const int* in_sizes, int n_in,
                              void* d_out, int out_size, void* d_ws, size_t ws_size,
                              hipStream_t stream) {
    const float* x  = (const float*)d_in[0];
    const int*   z  = (const int*)d_in[1];
    const float* s  = (const float*)d_in[2];
    const float* bw = (const float*)d_in[3];
    float* y = (float*)d_out;
    unsigned short* wpk = (unsigned short*)d_ws;   // 32*64*160*2 = 655 KB

    steer_weights<<<dim3(8, B_N), dim3(256), 0, stream>>>(z, s, bw, wpk);
    steer_conv_mfma<<<dim3(L_LEN / LGRP, B_N), dim3(128), 0, stream>>>(x, wpk, y);
}

// Round 16
// 135.648 us; speedup vs baseline: 1.2262x; 1.2262x over previous
//
#include <hip/hip_runtime.h>
#include <math.h>

#define KW 65
#define L_LEN 65536
#define B_N 32
#define OC_N 64
#define KPAD 160      // two 80-wide channel sections
#define SEC 80
#define LT 256        // l per tile
#define NT 8          // tiles per block
#define LGRP (LT*NT)  // 2048 l per block
#define XBASE 344     // base (phase-0) window length in shorts, mult of 8

typedef __attribute__((ext_vector_type(8))) short short8;
typedef __attribute__((ext_vector_type(4))) short short4v;
typedef __attribute__((ext_vector_type(4))) float f32x4;

__device__ __forceinline__ unsigned short f2bf(float f) {
    unsigned u = __builtin_bit_cast(unsigned, f);
    unsigned r = u + 0x7FFFu + ((u >> 16) & 1u);
    return (unsigned short)(r >> 16);
}

__device__ __forceinline__ float nan0(float v) {
    if (isnan(v)) return 0.0f;
    if (isinf(v)) return v > 0.0f ? 3.4028234663852886e38f : -3.4028234663852886e38f;
    return v;
}

// LDS-only workgroup barrier (validated in R8): IR-level local fences + raw
// s_barrier. Does NOT drain vmcnt — stores/loads stay in flight across it.
__device__ __forceinline__ void barrier_lds() {
    __builtin_amdgcn_fence(__ATOMIC_RELEASE, "workgroup", "local");
    __builtin_amdgcn_s_barrier();
    __builtin_amdgcn_fence(__ATOMIC_ACQUIRE, "workgroup", "local");
}

// ---------------- Kernel A: steered weights, packed bf16 [B][OC][160] -------
// grid (8, B): block handles batch b x 8 ocs -> short latency chains.
__global__ __launch_bounds__(256) void steer_weights(
        const int* __restrict__ z, const float* __restrict__ s,
        const float* __restrict__ bw, unsigned short* __restrict__ wpk) {
    const float PI = 3.14159265358979323846f;
    const float FS = 50000000.0f;
    int ocg = blockIdx.x;
    int b   = blockIdx.y;
    int t   = threadIdx.x;

    const int*   zb = z + b * 5;
    const float* sb = s + b * 5;
    float f0    = (zb[0] > 0) ? nan0(sb[0]) : 0.0f;
    float alpha = (zb[1] > 0) ? nan0(sb[1]) : 1.0f;
    float gain  = (zb[2] > 0) ? nan0(sb[2]) : 1.0f;
    float shf   = (zb[3] > 0) ? nan0(sb[3]) : 0.0f;
    float chirp = (zb[4] > 0) ? nan0(sb[4]) : 0.0f;

    float a = fmaxf(alpha, 0.001f);
    float Nf_raw = rintf(65.0f / a);          // jnp.round = half-to-even
    int   N  = (int)fminf(fmaxf(Nf_raw, 1.0f), 130.0f);
    float Nf = (float)N;
    int   sh = (int)rintf(shf);

    __shared__ float rw[8][2][KW];
    __shared__ float cph[KW], sph[KW];
    __shared__ int   j0t[KW], j1t[KW];
    __shared__ float w2t[KW];
    __shared__ int   i0t[130], i1t[130];
    __shared__ float w1t[130];

    if (t < KW) {
        float n  = (float)t;
        float tt = n / FS;
        float phi = 2.0f * PI * f0 * n / FS + PI * chirp * tt * tt;
        cph[t] = cosf(phi);
        sph[t] = sinf(phi);
        float c2  = fmaxf(((float)t + 0.5f) * (Nf / 65.0f) - 0.5f, 0.0f);
        float j0f = floorf(c2);
        j0t[t] = (int)j0f;
        j1t[t] = min((int)j0f + 1, N - 1);
        w2t[t] = c2 - j0f;
    } else if (t < KW + 130) {
        int j = t - KW;
        float c   = fmaxf(((float)j + 0.5f) * (65.0f / Nf) - 0.5f, 0.0f);
        float i0f = floorf(c);
        int   i0  = min((int)i0f, KW - 1);
        i0t[j] = i0;
        i1t[j] = min(i0 + 1, KW - 1);
        w1t[j] = c - i0f;
    }
    __syncthreads();

    // resample: 16 rows x 65 taps via table lerps
    for (int item = t; item < 16 * KW; item += 256) {
        int row = item / KW, i = item % KW;     // row = ocl*2 + ch
        const float* w = bw + (((ocg * 8 + (row >> 1)) * 2) + (row & 1)) * KW;
        int j0 = j0t[i], j1 = j1t[i];
        float v0 = (1.0f - w1t[j0]) * w[i0t[j0]] + w1t[j0] * w[i1t[j0]];
        float v1 = (1.0f - w1t[j1]) * w[i0t[j1]] + w1t[j1] * w[i1t[j1]];
        rw[row >> 1][row & 1][i] = (1.0f - w2t[i]) * v0 + w2t[i] * v1;
    }
    __syncthreads();

    int sh0 = ((sh % KW) + KW) % KW;
    // mix + gain + shift + pack
    for (int item = t; item < 8 * KW; item += 256) {
        int ocl = item / KW, k = item % KW;
        unsigned short* ob = wpk + ((size_t)b * OC_N + ocg * 8 + ocl) * KPAD;
        float I = rw[ocl][0][k], Q = rw[ocl][1][k];
        float cp = cph[k], sp = sph[k];
        float Ip = (I * cp - Q * sp) * gain;
        float Qp = (I * sp + Q * cp) * gain;
        int kk = k + sh0; if (kk >= KW) kk -= KW;
        ob[kk]       = f2bf(Ip);
        ob[SEC + kk] = f2bf(Qp);
    }
    // zero padding taps 65..79 of both sections
    for (int item = t; item < 8 * 30; item += 256) {
        int ocl = item / 30, rem = item % 30;
        int sec = rem / 15, kk = KW + rem % 15;
        unsigned short* ob = wpk + ((size_t)b * OC_N + ocg * 8 + ocl) * KPAD;
        ob[sec * SEC + kk] = 0;
    }
}

// ---------------- Kernel B: implicit-GEMM conv via bf16 MFMA -----------------
// R12 verbatim (64 oc x 2048 l per block, 8 tiles of 256, 4 waves, 4-phase
// copies with l = 64q+4c+p, contiguous f32x4 stores, launch_bounds (256,3))
// with COUNTED store pacing: barrier_lds (no vmcnt drain, validated R8) +
// explicit s_waitcnt vmcnt(16) after each tile's stores. Caps every wave at
// ~1 tile of stores in flight (fixes R8's builder-wave vmcnt-queue overflow)
// while removing R12's drain-to-0 at both barriers (T4: counted, never 0,
// never unbounded).
__global__ __launch_bounds__(256, 3) void steer_conv_mfma(
        const float* __restrict__ x, const unsigned short* __restrict__ wpk,
        float* __restrict__ y) {
    int b   = blockIdx.y;
    int L0  = blockIdx.x * LGRP;
    int tid = threadIdx.x;
    int wv = tid >> 6, lane = tid & 63;
    int c = lane & 15, g = lane >> 4;
    int a = wv & 1, lsub = wv >> 1;

    __shared__ __align__(16) unsigned short xt[2][4][2][XBASE];  // 11 KB

    // A fragments (weights) loaded once per block
    short8 afr[2][5];
    #pragma unroll
    for (int ot = 0; ot < 2; ++ot) {
        const unsigned short* wb = wpk + ((size_t)b * OC_N + 32 * a + 16 * ot + c) * KPAD;
        #pragma unroll
        for (int s = 0; s < 5; ++s)
            afr[ot][s] = *(const short8*)(wb + 32 * s + 8 * g);
    }

    const float* xb = x + (size_t)b * 2 * L_LEN;

    bool isLoader = (tid >= 84);
    int lidx = tid - 84;
    int lch = lidx / 86, li4 = lidx % 86;

    // per-lane B-fragment base (shorts) within a phase copy, per k-step;
    // actual read at boff[s] + 64*q + 4*c (8B aligned)
    int boff[5];
    #pragma unroll
    for (int s = 0; s < 5; ++s) {
        int k0 = 32 * s + 8 * g;
        int ch = (k0 >= SEC) ? 1 : 0;
        int t0 = k0 - SEC * ch;
        boff[s] = ch * XBASE + 128 * lsub + t0;
    }

    auto loadwin = [&](int l0) -> float4 {
        int gi = l0 - 32 + 4 * li4;
        float4 v;
        if (gi >= 0 && gi + 3 < L_LEN) {
            v = *(const float4*)(xb + (size_t)lch * L_LEN + gi);
        } else {
            float tmp[4];
            #pragma unroll
            for (int u = 0; u < 4; ++u) {
                int q = gi + u;
                tmp[u] = (q >= 0 && q < L_LEN) ? xb[(size_t)lch * L_LEN + q] : 0.0f;
            }
            v = make_float4(tmp[0], tmp[1], tmp[2], tmp[3]);
        }
        return v;
    };

    float4 v = make_float4(0.f, 0.f, 0.f, 0.f);
    if (isLoader) v = loadwin(L0);

    int cur = 0;
    for (int t = 0; t < NT; ++t) {
        int l0 = L0 + t * LT;
        // write bf16 base copy (phase 0) of tile t
        if (isLoader) {
            unsigned r0 = (unsigned)f2bf(v.x) | ((unsigned)f2bf(v.y) << 16);
            unsigned r1 = (unsigned)f2bf(v.z) | ((unsigned)f2bf(v.w) << 16);
            *(uint2*)&xt[cur][0][lch][4 * li4] = make_uint2(r0, r1);
        }
        barrier_lds();
        if (tid < 84) {
            // build phases 1..3 by 16-bit funnel shifts of the base copy
            int ch = tid / 42, j = tid % 42;
            const unsigned* src = (const unsigned*)&xt[cur][0][ch][8 * j];
            unsigned d[8];
            #pragma unroll
            for (int i = 0; i < 8; ++i) d[i] = src[i];
            #pragma unroll
            for (int p = 1; p < 4; ++p) {
                int q = p >> 1;
                unsigned o[4];
                #pragma unroll
                for (int i = 0; i < 4; ++i)
                    o[i] = (p & 1) ? ((d[i + q] >> 16) | (d[i + q + 1] << 16)) : d[i + q];
                *(uint4*)&xt[cur][p][ch][8 * j] = make_uint4(o[0], o[1], o[2], o[3]);
            }
        } else if (t + 1 < NT) {
            // prefetch next tile's window into registers
            v = loadwin(l0 + LT);
        }
        barrier_lds();

        f32x4 acc[2][2][4];   // [ot][q][p]
        #pragma unroll
        for (int ot = 0; ot < 2; ++ot)
            #pragma unroll
            for (int q = 0; q < 2; ++q)
                #pragma unroll
                for (int p = 0; p < 4; ++p) acc[ot][q][p] = (f32x4){0.f, 0.f, 0.f, 0.f};

        #pragma unroll
        for (int q = 0; q < 2; ++q) {
            #pragma unroll
            for (int p = 0; p < 4; ++p) {
                const unsigned short* xp = &xt[cur][p][0][0] + 64 * q + 4 * c;
                #pragma unroll
                for (int s = 0; s < 5; ++s) {
                    union { short4v h[2]; short8 v8; } u;
                    u.h[0] = *(const short4v*)(xp + boff[s]);
                    u.h[1] = *(const short4v*)(xp + boff[s] + 4);
                    short8 bfr = u.v8;
                    acc[0][q][p] = __builtin_amdgcn_mfma_f32_16x16x32_bf16(afr[0][s], bfr, acc[0][q][p], 0, 0, 0);
                    acc[1][q][p] = __builtin_amdgcn_mfma_f32_16x16x32_bf16(afr[1][s], bfr, acc[1][q][p], 0, 0, 0);
                }
            }
        }

        // store: per (ot,q,r) one contiguous f32x4 at l = l0+128*lsub+64q+4c
        #pragma unroll
        for (int ot = 0; ot < 2; ++ot) {
            #pragma unroll
            for (int q = 0; q < 2; ++q) {
                #pragma unroll
                for (int r = 0; r < 4; ++r) {
                    int oc = 32 * a + 16 * ot + 4 * g + r;
                    float* yr = y + ((size_t)b * OC_N + oc) * L_LEN + l0 + 128 * lsub + 64 * q + 4 * c;
                    *(f32x4*)yr = (f32x4){ acc[ot][q][0][r], acc[ot][q][1][r],
                                           acc[ot][q][2][r], acc[ot][q][3][r] };
                }
            }
        }
        // counted pacing: keep this tile's 16 stores in flight, drain older
        asm volatile("s_waitcnt vmcnt(16)" ::: "memory");
        cur ^= 1;
    }
}

extern "C" void kernel_launch(void* const* d_in, const int* in_sizes, int n_in,
                              void* d_out, int out_size, void* d_ws, size_t ws_size,
                              hipStream_t stream) {
    const float* x  = (const float*)d_in[0];
    const int*   z  = (const int*)d_in[1];
    const float* s  = (const float*)d_in[2];
    const float* bw = (const float*)d_in[3];
    float* y = (float*)d_out;
    unsigned short* wpk = (unsigned short*)d_ws;   // 32*64*160*2 = 655 KB

    steer_weights<<<dim3(8, B_N), dim3(256), 0, stream>>>(z, s, bw, wpk);
    steer_conv_mfma<<<dim3(L_LEN / LGRP, B_N), dim3(256), 0, stream>>>(x, wpk, y);
}

// Round 17
// 134.374 us; speedup vs baseline: 1.2378x; 1.0095x over previous
//
#include <hip/hip_runtime.h>
#include <math.h>

#define KW 65
#define L_LEN 65536
#define B_N 32
#define OC_N 64
#define KPAD 160      // two 80-wide channel sections
#define SEC 80
#define LT 256        // l per tile
#define NT 8          // tiles per block
#define LGRP (LT*NT)  // 2048 l per block
#define XBASE 344     // base (phase-0) window length in shorts, mult of 8

typedef __attribute__((ext_vector_type(8))) short short8;
typedef __attribute__((ext_vector_type(4))) short short4v;
typedef __attribute__((ext_vector_type(4))) float f32x4;

__device__ __forceinline__ unsigned short f2bf(float f) {
    unsigned u = __builtin_bit_cast(unsigned, f);
    unsigned r = u + 0x7FFFu + ((u >> 16) & 1u);
    return (unsigned short)(r >> 16);
}

__device__ __forceinline__ float nan0(float v) {
    if (isnan(v)) return 0.0f;
    if (isinf(v)) return v > 0.0f ? 3.4028234663852886e38f : -3.4028234663852886e38f;
    return v;
}

// ---------------- Kernel A: steered weights, packed bf16 [B][OC][160] -------
// grid (8, B): block handles batch b x 8 ocs -> short latency chains.
__global__ __launch_bounds__(256) void steer_weights(
        const int* __restrict__ z, const float* __restrict__ s,
        const float* __restrict__ bw, unsigned short* __restrict__ wpk) {
    const float PI = 3.14159265358979323846f;
    const float FS = 50000000.0f;
    int ocg = blockIdx.x;
    int b   = blockIdx.y;
    int t   = threadIdx.x;

    const int*   zb = z + b * 5;
    const float* sb = s + b * 5;
    float f0    = (zb[0] > 0) ? nan0(sb[0]) : 0.0f;
    float alpha = (zb[1] > 0) ? nan0(sb[1]) : 1.0f;
    float gain  = (zb[2] > 0) ? nan0(sb[2]) : 1.0f;
    float shf   = (zb[3] > 0) ? nan0(sb[3]) : 0.0f;
    float chirp = (zb[4] > 0) ? nan0(sb[4]) : 0.0f;

    float a = fmaxf(alpha, 0.001f);
    float Nf_raw = rintf(65.0f / a);          // jnp.round = half-to-even
    int   N  = (int)fminf(fmaxf(Nf_raw, 1.0f), 130.0f);
    float Nf = (float)N;
    int   sh = (int)rintf(shf);

    __shared__ float rw[8][2][KW];
    __shared__ float cph[KW], sph[KW];
    __shared__ int   j0t[KW], j1t[KW];
    __shared__ float w2t[KW];
    __shared__ int   i0t[130], i1t[130];
    __shared__ float w1t[130];

    if (t < KW) {
        float n  = (float)t;
        float tt = n / FS;
        float phi = 2.0f * PI * f0 * n / FS + PI * chirp * tt * tt;
        cph[t] = cosf(phi);
        sph[t] = sinf(phi);
        float c2  = fmaxf(((float)t + 0.5f) * (Nf / 65.0f) - 0.5f, 0.0f);
        float j0f = floorf(c2);
        j0t[t] = (int)j0f;
        j1t[t] = min((int)j0f + 1, N - 1);
        w2t[t] = c2 - j0f;
    } else if (t < KW + 130) {
        int j = t - KW;
        float c   = fmaxf(((float)j + 0.5f) * (65.0f / Nf) - 0.5f, 0.0f);
        float i0f = floorf(c);
        int   i0  = min((int)i0f, KW - 1);
        i0t[j] = i0;
        i1t[j] = min(i0 + 1, KW - 1);
        w1t[j] = c - i0f;
    }
    __syncthreads();

    // resample: 16 rows x 65 taps via table lerps
    for (int item = t; item < 16 * KW; item += 256) {
        int row = item / KW, i = item % KW;     // row = ocl*2 + ch
        const float* w = bw + (((ocg * 8 + (row >> 1)) * 2) + (row & 1)) * KW;
        int j0 = j0t[i], j1 = j1t[i];
        float v0 = (1.0f - w1t[j0]) * w[i0t[j0]] + w1t[j0] * w[i1t[j0]];
        float v1 = (1.0f - w1t[j1]) * w[i0t[j1]] + w1t[j1] * w[i1t[j1]];
        rw[row >> 1][row & 1][i] = (1.0f - w2t[i]) * v0 + w2t[i] * v1;
    }
    __syncthreads();

    int sh0 = ((sh % KW) + KW) % KW;
    // mix + gain + shift + pack
    for (int item = t; item < 8 * KW; item += 256) {
        int ocl = item / KW, k = item % KW;
        unsigned short* ob = wpk + ((size_t)b * OC_N + ocg * 8 + ocl) * KPAD;
        float I = rw[ocl][0][k], Q = rw[ocl][1][k];
        float cp = cph[k], sp = sph[k];
        float Ip = (I * cp - Q * sp) * gain;
        float Qp = (I * sp + Q * cp) * gain;
        int kk = k + sh0; if (kk >= KW) kk -= KW;
        ob[kk]       = f2bf(Ip);
        ob[SEC + kk] = f2bf(Qp);
    }
    // zero padding taps 65..79 of both sections
    for (int item = t; item < 8 * 30; item += 256) {
        int ocl = item / 30, rem = item % 30;
        int sec = rem / 15, kk = KW + rem % 15;
        unsigned short* ob = wpk + ((size_t)b * OC_N + ocg * 8 + ocl) * KPAD;
        ob[sec * SEC + kk] = 0;
    }
}

// ---------------- Kernel B: implicit-GEMM conv via bf16 MFMA -----------------
// R12 verbatim (64 oc x 2048 l per block, 8 tiles of 256, 4 waves, 4-phase
// copies with l = 64q+4c+p, contiguous f32x4 stores, 2 __syncthreads/tile,
// launch_bounds (256,3)). ONE change: bijective XCD-aware block swizzle (T1).
// Grid 1024 = 8 XCDs x 128: XCD k owns batches [4k,4k+4) -> each XCD writes
// one contiguous 64 MB slab of y and reads only 2.1 MB of x (L2-resident).
__global__ __launch_bounds__(256, 3) void steer_conv_mfma(
        const float* __restrict__ x, const unsigned short* __restrict__ wpk,
        float* __restrict__ y) {
    // XCD swizzle: linear id -> (b, l-group) so each XCD gets 4 whole batches
    int id  = blockIdx.x;           // 0..1023, dispatched round-robin over 8 XCDs
    int xcd = id & 7;               // physical XCD (id % 8)
    int j   = id >> 3;              // 0..127 within XCD
    int b   = xcd * 4 + (j >> 5);   // 4 consecutive batches per XCD
    int L0  = (j & 31) * LGRP;

    int tid = threadIdx.x;
    int wv = tid >> 6, lane = tid & 63;
    int c = lane & 15, g = lane >> 4;
    int a = wv & 1, lsub = wv >> 1;

    __shared__ __align__(16) unsigned short xt[2][4][2][XBASE];  // 11 KB

    // A fragments (weights) loaded once per block
    short8 afr[2][5];
    #pragma unroll
    for (int ot = 0; ot < 2; ++ot) {
        const unsigned short* wb = wpk + ((size_t)b * OC_N + 32 * a + 16 * ot + c) * KPAD;
        #pragma unroll
        for (int s = 0; s < 5; ++s)
            afr[ot][s] = *(const short8*)(wb + 32 * s + 8 * g);
    }

    const float* xb = x + (size_t)b * 2 * L_LEN;

    bool isLoader = (tid >= 84);
    int lidx = tid - 84;
    int lch = lidx / 86, li4 = lidx % 86;

    // per-lane B-fragment base (shorts) within a phase copy, per k-step;
    // actual read at boff[s] + 64*q + 4*c (8B aligned)
    int boff[5];
    #pragma unroll
    for (int s = 0; s < 5; ++s) {
        int k0 = 32 * s + 8 * g;
        int ch = (k0 >= SEC) ? 1 : 0;
        int t0 = k0 - SEC * ch;
        boff[s] = ch * XBASE + 128 * lsub + t0;
    }

    auto loadwin = [&](int l0) -> float4 {
        int gi = l0 - 32 + 4 * li4;
        float4 v;
        if (gi >= 0 && gi + 3 < L_LEN) {
            v = *(const float4*)(xb + (size_t)lch * L_LEN + gi);
        } else {
            float tmp[4];
            #pragma unroll
            for (int u = 0; u < 4; ++u) {
                int q = gi + u;
                tmp[u] = (q >= 0 && q < L_LEN) ? xb[(size_t)lch * L_LEN + q] : 0.0f;
            }
            v = make_float4(tmp[0], tmp[1], tmp[2], tmp[3]);
        }
        return v;
    };

    float4 v = make_float4(0.f, 0.f, 0.f, 0.f);
    if (isLoader) v = loadwin(L0);

    int cur = 0;
    for (int t = 0; t < NT; ++t) {
        int l0 = L0 + t * LT;
        // write bf16 base copy (phase 0) of tile t
        if (isLoader) {
            unsigned r0 = (unsigned)f2bf(v.x) | ((unsigned)f2bf(v.y) << 16);
            unsigned r1 = (unsigned)f2bf(v.z) | ((unsigned)f2bf(v.w) << 16);
            *(uint2*)&xt[cur][0][lch][4 * li4] = make_uint2(r0, r1);
        }
        __syncthreads();
        if (tid < 84) {
            // build phases 1..3 by 16-bit funnel shifts of the base copy
            int ch = tid / 42, j2 = tid % 42;
            const unsigned* src = (const unsigned*)&xt[cur][0][ch][8 * j2];
            unsigned d[8];
            #pragma unroll
            for (int i = 0; i < 8; ++i) d[i] = src[i];
            #pragma unroll
            for (int p = 1; p < 4; ++p) {
                int q = p >> 1;
                unsigned o[4];
                #pragma unroll
                for (int i = 0; i < 4; ++i)
                    o[i] = (p & 1) ? ((d[i + q] >> 16) | (d[i + q + 1] << 16)) : d[i + q];
                *(uint4*)&xt[cur][p][ch][8 * j2] = make_uint4(o[0], o[1], o[2], o[3]);
            }
        } else if (t + 1 < NT) {
            // prefetch next tile's window into registers
            v = loadwin(l0 + LT);
        }
        __syncthreads();

        f32x4 acc[2][2][4];   // [ot][q][p]
        #pragma unroll
        for (int ot = 0; ot < 2; ++ot)
            #pragma unroll
            for (int q = 0; q < 2; ++q)
                #pragma unroll
                for (int p = 0; p < 4; ++p) acc[ot][q][p] = (f32x4){0.f, 0.f, 0.f, 0.f};

        #pragma unroll
        for (int q = 0; q < 2; ++q) {
            #pragma unroll
            for (int p = 0; p < 4; ++p) {
                const unsigned short* xp = &xt[cur][p][0][0] + 64 * q + 4 * c;
                #pragma unroll
                for (int s = 0; s < 5; ++s) {
                    union { short4v h[2]; short8 v8; } u;
                    u.h[0] = *(const short4v*)(xp + boff[s]);
                    u.h[1] = *(const short4v*)(xp + boff[s] + 4);
                    short8 bfr = u.v8;
                    acc[0][q][p] = __builtin_amdgcn_mfma_f32_16x16x32_bf16(afr[0][s], bfr, acc[0][q][p], 0, 0, 0);
                    acc[1][q][p] = __builtin_amdgcn_mfma_f32_16x16x32_bf16(afr[1][s], bfr, acc[1][q][p], 0, 0, 0);
                }
            }
        }

        // store: per (ot,q,r) one contiguous f32x4 at l = l0+128*lsub+64q+4c
        #pragma unroll
        for (int ot = 0; ot < 2; ++ot) {
            #pragma unroll
            for (int q = 0; q < 2; ++q) {
                #pragma unroll
                for (int r = 0; r < 4; ++r) {
                    int oc = 32 * a + 16 * ot + 4 * g + r;
                    float* yr = y + ((size_t)b * OC_N + oc) * L_LEN + l0 + 128 * lsub + 64 * q + 4 * c;
                    *(f32x4*)yr = (f32x4){ acc[ot][q][0][r], acc[ot][q][1][r],
                                           acc[ot][q][2][r], acc[ot][q][3][r] };
                }
            }
        }
        cur ^= 1;
    }
}

extern "C" void kernel_launch(void* const* d_in, const int* in_sizes, int n_in,
                              void* d_out, int out_size, void* d_ws, size_t ws_size,
                              hipStream_t stream) {
    const float* x  = (const float*)d_in[0];
    const int*   z  = (const int*)d_in[1];
    const float* s  = (const float*)d_in[2];
    const float* bw = (const float*)d_in[3];
    float* y = (float*)d_out;
    unsigned short* wpk = (unsigned short*)d_ws;   // 32*64*160*2 = 655 KB

    steer_weights<<<dim3(8, B_N), dim3(256), 0, stream>>>(z, s, bw, wpk);
    steer_conv_mfma<<<dim3(L_LEN / LGRP * B_N), dim3(256), 0, stream>>>(x, wpk, y);
}